// Round 16
// baseline (83.941 us; speedup 1.0000x reference)
//
#include <hip/hip_runtime.h>
#include <stdint.h>

// ReadoutInterpolator — VERIFIED world model (R15 PASS, absmax 0.03125):
//   d_in[0] c: f32 1e6 | d_in[1] ksp_real: f32 8x8192 | d_in[2] ksp_imag: f32 8x8192
//   d_out: f32 16e6 = 64 MB, planar-global stack([out.real, out.imag]) -> (2, 8, 1e6):
//     re at [coil*npts + p], im at [8*npts + coil*npts + p]
//
// R16 OPTIMIZATION (from R15's cycle model: writes ~10.9us/CU floor; LDS ~7.5us;
// VALU ~10us — compute co-dominant with the write floor):
//  1. TAP-2 ELISION: d = x0-kx in [-1,0] => w2 = max(0,1-|d+2|) == 0 identically.
//     The reference adds exactly +0.0 for tap 2 => dropping it is bit-safe.
//     Weights collapse to w0 = 1+d (same rounding as ref's 1-|d|), w1 = -d
//     (<=1 ulp vs ref's 1-|d+1|; negligible vs 0.031 bf16-quant error).
//  2. WRAP PAD: sk[8192] = sk[0] => i1 = i0+1 with NO mod => both taps are
//     adjacent dwords from one base => compiler fuses to one ds_read2_b32.
//     LDS instructions per instance: 3 -> 1. (i0 = (int)x0 & 8191 still handles
//     the x0 = -1 edge: i0 = 8191, i1 = 8192 -> pad = sk[0] = mod semantics.)
//  3. Occupancy: 32 KB LDS allows 5 blocks/CU -> kChunks 160 (1280 blocks).
// Predicted kernel time ~15us (write-BW-bound), SQ_LDS_BANK_CONFLICT ~-50%.

namespace {
constexpr int kNCoil  = 8;
constexpr int kNOS    = 8192;   // oversampled readout length (power of 2)
constexpr int kBlock  = 256;
constexpr int kChunks = 160;    // 160*8 = 1280 blocks = 5/CU at 32 KB LDS

__device__ __forceinline__ float bf16lo_to_f32(uint32_t u) {
    union { uint32_t u; float f; } v; v.u = u << 16; return v.f;
}
__device__ __forceinline__ float bf16hi_to_f32(uint32_t u) {
    union { uint32_t u; float f; } v; v.u = u & 0xffff0000u; return v.f;
}
__device__ __forceinline__ uint32_t f32_to_bf16_rne(float f) {
    union { float f; uint32_t u; } v; v.f = f;
    return (v.u + 0x7fffu + ((v.u >> 16) & 1u)) >> 16;
}
} // namespace

__global__ __launch_bounds__(kBlock) void ReadoutInterpolator_54030688583962_kernel(
    const float* __restrict__ c,          // float32, npts
    const float* __restrict__ ksp_real,   // float32, 8*8192
    const float* __restrict__ ksp_imag,   // float32, 8*8192
    float* __restrict__ out,              // f32 planar: [re (8*npts) | im (8*npts)]
    int npts,
    int out_f32_max)                      // total f32 slots = out_size
{
    __shared__ uint32_t sk[kNOS + 1];     // +1 wrap pad: sk[8192] = sk[0]

    const int coil = blockIdx.y;
    const int tid  = threadIdx.x;

    // ---- Stage coil row into LDS as packed bf16 pairs (float4 global loads) ----
    {
        const float4* __restrict__ rv = (const float4*)(ksp_real + (size_t)coil * kNOS);
        const float4* __restrict__ iv = (const float4*)(ksp_imag + (size_t)coil * kNOS);
        for (int i = tid; i < kNOS / 4; i += kBlock) {
            const float4 r = rv[i];
            const float4 m = iv[i];
            const int b = i * 4;
            sk[b + 0] = f32_to_bf16_rne(r.x) | (f32_to_bf16_rne(m.x) << 16);
            sk[b + 1] = f32_to_bf16_rne(r.y) | (f32_to_bf16_rne(m.y) << 16);
            sk[b + 2] = f32_to_bf16_rne(r.z) | (f32_to_bf16_rne(m.z) << 16);
            sk[b + 3] = f32_to_bf16_rne(r.w) | (f32_to_bf16_rne(m.w) << 16);
        }
        if (tid == 0) {   // wrap pad, loaded independently from global (no LDS RAW)
            sk[kNOS] = f32_to_bf16_rne(ksp_real[(size_t)coil * kNOS])
                     | (f32_to_bf16_rne(ksp_imag[(size_t)coil * kNOS]) << 16);
        }
    }
    __syncthreads();

    const int planeOff = kNCoil * npts;   // imag plane start (f32 elements)

    const int nq     = npts >> 2;                          // 4-point quads
    const int chunkQ = (nq + (int)gridDim.x - 1) / (int)gridDim.x;
    const int q0     = blockIdx.x * chunkQ;
    const int q1     = min(nq, q0 + chunkQ);

    const float4* __restrict__ c4 = (const float4*)c;

    for (int q = q0 + tid; q < q1; q += kBlock) {
        const float4 cv = c4[q];
        const float kx[4] = {cv.x * 4.0f, cv.y * 4.0f, cv.z * 4.0f, cv.w * 4.0f};

        float re[4], im[4];
        #pragma unroll
        for (int j = 0; j < 4; ++j) {
            const float x0 = ceilf(kx[j] - 1.0f);
            const float d  = x0 - kx[j];                    // exact; in [-1, 0]
            const float w0 = 1.0f + d;                      // == ref's 1-|d|
            const float w1 = -d;                            // ~= ref's 1-|d+1| (<=1 ulp)
            const int i0 = ((int)x0) & (kNOS - 1);          // x0=-1 -> 8191, i1 -> pad
            const uint32_t g0 = sk[i0];
            const uint32_t g1 = sk[i0 + 1];                 // fuses to ds_read2_b32
            re[j] = fmaf(w1, bf16lo_to_f32(g1), w0 * bf16lo_to_f32(g0));
            im[j] = fmaf(w1, bf16hi_to_f32(g1), w0 * bf16hi_to_f32(g0));
        }

        // planar-global: re at coil*npts + p, im at planeOff + coil*npts + p
        const int rbase = coil * npts + 4 * q;
        const int ibase = planeOff + rbase;
        if (ibase + 4 <= out_f32_max) {                     // rbase < ibase always
            *((float4*)(out + rbase)) = make_float4(re[0], re[1], re[2], re[3]);
            *((float4*)(out + ibase)) = make_float4(im[0], im[1], im[2], im[3]);
        } else {
            #pragma unroll
            for (int j = 0; j < 4; ++j) {
                if (rbase + j < out_f32_max) out[rbase + j] = re[j];
                if (ibase + j < out_f32_max) out[ibase + j] = im[j];
            }
        }
    }

    // ---- Scalar tail (npts % 4 != 0) — last x-block only ----
    if (blockIdx.x == gridDim.x - 1) {
        for (int p = (nq << 2) + tid; p < npts; p += kBlock) {
            const float kxs = c[p] * 4.0f;
            const float x0 = ceilf(kxs - 1.0f);
            const float d  = x0 - kxs;
            const float w0 = 1.0f + d;
            const float w1 = -d;
            const int i0 = ((int)x0) & (kNOS - 1);
            const uint32_t g0 = sk[i0];
            const uint32_t g1 = sk[i0 + 1];
            const float re = fmaf(w1, bf16lo_to_f32(g1), w0 * bf16lo_to_f32(g0));
            const float im = fmaf(w1, bf16hi_to_f32(g1), w0 * bf16hi_to_f32(g0));
            const int rbase = coil * npts + p;
            const int ibase = planeOff + rbase;
            if (rbase < out_f32_max) out[rbase] = re;
            if (ibase < out_f32_max) out[ibase] = im;
        }
    }
}

extern "C" void kernel_launch(void* const* d_in, const int* in_sizes, int n_in,
                              void* d_out, int out_size, void* d_ws, size_t ws_size,
                              hipStream_t stream) {
    const float* c        = (const float*)d_in[0];
    const float* ksp_real = (const float*)d_in[1];
    const float* ksp_imag = (const float*)d_in[2];
    float*       out      = (float*)d_out;

    const int npts = in_sizes[0];   // c is (NPTS, 1) -> NPTS elements

    dim3 grid(kChunks, kNCoil);
    ReadoutInterpolator_54030688583962_kernel<<<grid, kBlock, 0, stream>>>(
        c, ksp_real, ksp_imag, out, npts, out_size);
}

// Round 17
// 78.033 us; speedup vs baseline: 1.0757x; 1.0757x over previous
//
#include <hip/hip_runtime.h>
#include <stdint.h>

// ReadoutInterpolator — VERIFIED world model (R15/R16 PASS, absmax 0.03125):
//   d_in[0] c: f32 1e6 | d_in[1] ksp_real: f32 8x8192 | d_in[2] ksp_imag: f32 8x8192
//   d_out: f32 16e6 = 64 MB planar-global stack([re, im]):
//     re at [coil*npts + p], im at [8*npts + coil*npts + p]
//
// R17: OCCUPANCY ROUND. dur_us decomposition: ~57 us is harness resets (top-5 are
// all fillBufferAligned at 6.3 TB/s); kernel ~23-27 us vs an ~11 us HBM floor
// (64 MB write + ~5 MB fetch). Gap = latency hiding: 256-thr blocks cap at
// 5 blocks x 4 waves = 20 waves/CU (LDS-limited). Fix: 512-thr blocks ->
// 4 blocks x 32 KB = 128 KB LDS, 32 waves/CU (hardware cap) with
// __launch_bounds__(512, 8) to keep VGPR <= 64.
// Also: x0 via floorf(kx) instead of ceilf(kx-1) — bit-identical output
// (at integer kx both pick the same sample with weight 1; elsewhere equal),
// one less VALU in the address chain. Tap-2 remains elided (w2 == 0).
// Wrap pad sk[8192]=sk[0] keeps the 2-tap gather a single ds_read2_b32.

namespace {
constexpr int kNCoil  = 8;
constexpr int kNOS    = 8192;   // oversampled readout length (power of 2)
constexpr int kBlock  = 512;    // 8 waves/block
constexpr int kChunks = 64;     // 64*8 = 512 blocks = 4/CU exactly, zero tail

__device__ __forceinline__ float bf16lo_to_f32(uint32_t u) {
    union { uint32_t u; float f; } v; v.u = u << 16; return v.f;
}
__device__ __forceinline__ float bf16hi_to_f32(uint32_t u) {
    union { uint32_t u; float f; } v; v.u = u & 0xffff0000u; return v.f;
}
__device__ __forceinline__ uint32_t f32_to_bf16_rne(float f) {
    union { float f; uint32_t u; } v; v.f = f;
    return (v.u + 0x7fffu + ((v.u >> 16) & 1u)) >> 16;
}
} // namespace

__global__ __launch_bounds__(kBlock, 8) void ReadoutInterpolator_54030688583962_kernel(
    const float* __restrict__ c,          // float32, npts
    const float* __restrict__ ksp_real,   // float32, 8*8192
    const float* __restrict__ ksp_imag,   // float32, 8*8192
    float* __restrict__ out,              // f32 planar: [re (8*npts) | im (8*npts)]
    int npts,
    int out_f32_max)                      // total f32 slots = out_size
{
    __shared__ uint32_t sk[kNOS + 1];     // +1 wrap pad: sk[8192] = sk[0]

    const int coil = blockIdx.y;
    const int tid  = threadIdx.x;

    // ---- Stage coil row into LDS as packed bf16 pairs (float4 global loads) ----
    {
        const float4* __restrict__ rv = (const float4*)(ksp_real + (size_t)coil * kNOS);
        const float4* __restrict__ iv = (const float4*)(ksp_imag + (size_t)coil * kNOS);
        for (int i = tid; i < kNOS / 4; i += kBlock) {
            const float4 r = rv[i];
            const float4 m = iv[i];
            const int b = i * 4;
            sk[b + 0] = f32_to_bf16_rne(r.x) | (f32_to_bf16_rne(m.x) << 16);
            sk[b + 1] = f32_to_bf16_rne(r.y) | (f32_to_bf16_rne(m.y) << 16);
            sk[b + 2] = f32_to_bf16_rne(r.z) | (f32_to_bf16_rne(m.z) << 16);
            sk[b + 3] = f32_to_bf16_rne(r.w) | (f32_to_bf16_rne(m.w) << 16);
        }
        if (tid == 0) {   // wrap pad, loaded straight from global (no LDS RAW)
            sk[kNOS] = f32_to_bf16_rne(ksp_real[(size_t)coil * kNOS])
                     | (f32_to_bf16_rne(ksp_imag[(size_t)coil * kNOS]) << 16);
        }
    }
    __syncthreads();

    const int planeOff = kNCoil * npts;   // imag plane start (f32 elements)

    const int nq     = npts >> 2;                          // 4-point quads
    const int chunkQ = (nq + (int)gridDim.x - 1) / (int)gridDim.x;
    const int q0     = blockIdx.x * chunkQ;
    const int q1     = min(nq, q0 + chunkQ);

    const float4* __restrict__ c4 = (const float4*)c;

    for (int q = q0 + tid; q < q1; q += kBlock) {
        const float4 cv = c4[q];
        const float kx[4] = {cv.x * 4.0f, cv.y * 4.0f, cv.z * 4.0f, cv.w * 4.0f};

        float re[4], im[4];
        #pragma unroll
        for (int j = 0; j < 4; ++j) {
            const float f  = floorf(kx[j]);                 // kx >= 0: trunc == floor
            const float d2 = kx[j] - f;                     // exact; in [0, 1)
            const float w0 = 1.0f - d2;
            const float w1 = d2;
            const int i0 = ((int)f) & (kNOS - 1);           // i0+1 may hit the pad
            const uint32_t g0 = sk[i0];
            const uint32_t g1 = sk[i0 + 1];                 // ds_read2_b32 fusion
            re[j] = fmaf(w1, bf16lo_to_f32(g1), w0 * bf16lo_to_f32(g0));
            im[j] = fmaf(w1, bf16hi_to_f32(g1), w0 * bf16hi_to_f32(g0));
        }

        // planar-global: re at coil*npts + p, im at planeOff + coil*npts + p
        const int rbase = coil * npts + 4 * q;
        const int ibase = planeOff + rbase;
        if (ibase + 4 <= out_f32_max) {                     // rbase < ibase always
            *((float4*)(out + rbase)) = make_float4(re[0], re[1], re[2], re[3]);
            *((float4*)(out + ibase)) = make_float4(im[0], im[1], im[2], im[3]);
        } else {
            #pragma unroll
            for (int j = 0; j < 4; ++j) {
                if (rbase + j < out_f32_max) out[rbase + j] = re[j];
                if (ibase + j < out_f32_max) out[ibase + j] = im[j];
            }
        }
    }

    // ---- Scalar tail (npts % 4 != 0) — last x-block only ----
    if (blockIdx.x == gridDim.x - 1) {
        for (int p = (nq << 2) + tid; p < npts; p += kBlock) {
            const float kxs = c[p] * 4.0f;
            const float f   = floorf(kxs);
            const float d2  = kxs - f;
            const float w0  = 1.0f - d2;
            const float w1  = d2;
            const int i0 = ((int)f) & (kNOS - 1);
            const uint32_t g0 = sk[i0];
            const uint32_t g1 = sk[i0 + 1];
            const float re = fmaf(w1, bf16lo_to_f32(g1), w0 * bf16lo_to_f32(g0));
            const float im = fmaf(w1, bf16hi_to_f32(g1), w0 * bf16hi_to_f32(g0));
            const int rbase = coil * npts + p;
            const int ibase = planeOff + rbase;
            if (rbase < out_f32_max) out[rbase] = re;
            if (ibase < out_f32_max) out[ibase] = im;
        }
    }
}

extern "C" void kernel_launch(void* const* d_in, const int* in_sizes, int n_in,
                              void* d_out, int out_size, void* d_ws, size_t ws_size,
                              hipStream_t stream) {
    const float* c        = (const float*)d_in[0];
    const float* ksp_real = (const float*)d_in[1];
    const float* ksp_imag = (const float*)d_in[2];
    float*       out      = (float*)d_out;

    const int npts = in_sizes[0];   // c is (NPTS, 1) -> NPTS elements

    dim3 grid(kChunks, kNCoil);
    ReadoutInterpolator_54030688583962_kernel<<<grid, kBlock, 0, stream>>>(
        c, ksp_real, ksp_imag, out, npts, out_size);
}